// Round 5
// baseline (49.186 us; speedup 1.0000x reference)
//
#include <hip/hip_runtime.h>

#define VOCAB 128000
#define HIST 512
#define ROW_F4 (VOCAB / 4)                 // 32000 float4 per row
#define CHUNKS_PER_ROW 8
#define CHUNK_F4 (ROW_F4 / CHUNKS_PER_ROW) // 4000 float4 per chunk
#define CHUNK_FLOATS (CHUNK_F4 * 4)        // 16000 floats per chunk

typedef float f32x4 __attribute__((ext_vector_type(4)));

// One block per (row, chunk): 2048 blocks x 256 threads.
// Cache policy: logits LOADS are nontemporal (streaming, don't allocate in
// Infinity Cache); out STORES are plain (allocate). out (131 MB) then fits
// the 256 MB IC alone -> across timed replays out stays dirty-resident
// (WRITE_SIZE -> ~0) while logits streams from HBM (FETCH_SIZE -> 131 MB).
// Net HBM traffic 193 -> ~131 MB vs R4.
// WAW hazard (copy vs penalty overwrite) stays intra-block: each block
// applies only the penalties whose index lands in its own chunk, after
// __syncthreads() (which drains vmcnt before the barrier).
__global__ __launch_bounds__(256)
void APPLY_PENALTY_5909874999394_fused(const f32x4* __restrict__ logits4,
                                       const float* __restrict__ logits,
                                       const int* __restrict__ save_id,
                                       const float* __restrict__ pval,
                                       const int* __restrict__ prange,
                                       f32x4* __restrict__ out4,
                                       float* __restrict__ out) {
    const int bid   = blockIdx.x;
    const int row   = bid >> 3;            // / CHUNKS_PER_ROW
    const int chunk = bid & 7;             // % CHUNKS_PER_ROW
    const long rowoff4 = (long)row * ROW_F4;
    const int  c0_4 = chunk * CHUNK_F4;

    // Phase 1: copy this chunk. Streaming loads, plain (allocating) stores.
    for (int j = threadIdx.x; j < CHUNK_F4; j += 256) {
        f32x4 v = __builtin_nontemporal_load(&logits4[rowoff4 + c0_4 + j]);
        out4[rowoff4 + c0_4 + j] = v;
    }

    __syncthreads();  // s_waitcnt vmcnt(0) before s_barrier — chunk copy done

    // Phase 2: penalties landing in [lo, hi) of this row (pr = 64 here).
    const int pr = *prange;
    const float p = *pval;
    const int lo = c0_4 * 4;
    const int hi = lo + CHUNK_FLOATS;
    const int base = row * HIST + (HIST - pr);
    const long rowoff = (long)row * VOCAB;
    for (int k = threadIdx.x; k < pr; k += 256) {
        const int idx = save_id[base + k];
        if (idx >= lo && idx < hi)
            out[rowoff + idx] = logits[rowoff + idx] * p;
    }
}

extern "C" void kernel_launch(void* const* d_in, const int* in_sizes, int n_in,
                              void* d_out, int out_size, void* d_ws, size_t ws_size,
                              hipStream_t stream) {
    const float* logits  = (const float*)d_in[0];
    const int*   save_id = (const int*)d_in[1];
    const float* pval    = (const float*)d_in[2];
    const int*   prange  = (const int*)d_in[3];
    float* out = (float*)d_out;

    const int rows = out_size / VOCAB;      // 256
    const int grid = rows * CHUNKS_PER_ROW; // 2048
    APPLY_PENALTY_5909874999394_fused<<<grid, 256, 0, stream>>>(
        (const f32x4*)logits, logits, save_id, pval, prange,
        (f32x4*)out, out);
}

// Round 6
// 44.939 us; speedup vs baseline: 1.0945x; 1.0945x over previous
//
#include <hip/hip_runtime.h>

#define VOCAB 128000
#define HIST 512
#define ROW_F4 (VOCAB / 4)        // 32000 float4 per row
#define CHUNKS_PER_ROW 25
#define CHUNK_F4 1280             // 32000 / 25
#define CHUNK_FLOATS (CHUNK_F4 * 4)  // 5120 floats
#define CHUNK_WORDS (CHUNK_FLOATS / 32) // 160 u32 bitmap words
#define F4_PER_THREAD 5           // 1280 / 256

typedef float f32x4 __attribute__((ext_vector_type(4)));

// Single-pass fused copy+penalty. One block per (row, chunk):
// 256 rows x 25 chunks = 6400 blocks x 256 threads.
//  1) load this row's pr save_ids (<=2 per thread), zero a 640B LDS bitmap,
//     barrier, atomicOr the in-chunk ids into the bitmap (idempotent for
//     duplicate ids), barrier. Only cheap LDS + 64 tiny loads drained here.
//  2) stream the chunk: 5 independent float4 loads per thread (unrolled,
//     MLP=5), apply p to bitmap-flagged lanes in-register, one plain store.
// Out is written exactly once -> no WAW, no mid-stream vmcnt(0) barrier,
// no second pass. Plain (caching) loads/stores: R5 proved NT loads regress.
__global__ __launch_bounds__(256)
void APPLY_PENALTY_5909874999394_fused(const f32x4* __restrict__ logits4,
                                       const int* __restrict__ save_id,
                                       const float* __restrict__ pval,
                                       const int* __restrict__ prange,
                                       f32x4* __restrict__ out4) {
    const int bid   = blockIdx.x;
    const int row   = bid / CHUNKS_PER_ROW;
    const int chunk = bid % CHUNKS_PER_ROW;
    const int tid   = threadIdx.x;

    const int pr = *prange;            // 64 at reference shapes (<=512 general)
    const float p = *pval;
    const int lo = chunk * CHUNK_FLOATS;

    __shared__ unsigned bm[CHUNK_WORDS];

    // Issue id loads early (overlap with bitmap zeroing).
    int id0 = -1, id1 = -1;
    const int base = row * HIST + (HIST - pr);
    if (tid < pr)       id0 = save_id[base + tid];
    if (tid + 256 < pr) id1 = save_id[base + tid + 256];

    if (tid < CHUNK_WORDS) bm[tid] = 0;
    __syncthreads();

    if (id0 >= lo && id0 < lo + CHUNK_FLOATS) {
        const int b = id0 - lo;
        atomicOr(&bm[b >> 5], 1u << (b & 31));
    }
    if (id1 >= lo && id1 < lo + CHUNK_FLOATS) {
        const int b = id1 - lo;
        atomicOr(&bm[b >> 5], 1u << (b & 31));
    }
    __syncthreads();

    // Streaming copy with inline penalty. f = f4 index within chunk.
    const long base4 = (long)row * ROW_F4 + (long)chunk * CHUNK_F4;
    #pragma unroll
    for (int i = 0; i < F4_PER_THREAD; ++i) {
        const int f = tid + i * 256;
        f32x4 v = logits4[base4 + f];
        const unsigned nib = (bm[f >> 3] >> ((f & 7) * 4)) & 0xFu;
        if (nib) {
            if (nib & 1u) v.x *= p;
            if (nib & 2u) v.y *= p;
            if (nib & 4u) v.z *= p;
            if (nib & 8u) v.w *= p;
        }
        out4[base4 + f] = v;
    }
}

extern "C" void kernel_launch(void* const* d_in, const int* in_sizes, int n_in,
                              void* d_out, int out_size, void* d_ws, size_t ws_size,
                              hipStream_t stream) {
    const float* logits  = (const float*)d_in[0];
    const int*   save_id = (const int*)d_in[1];
    const float* pval    = (const float*)d_in[2];
    const int*   prange  = (const int*)d_in[3];
    float* out = (float*)d_out;

    const int rows = out_size / VOCAB;            // 256
    const int grid = rows * CHUNKS_PER_ROW;       // 6400
    APPLY_PENALTY_5909874999394_fused<<<grid, 256, 0, stream>>>(
        (const f32x4*)logits, save_id, pval, prange, (f32x4*)out);
}